// Round 1
// baseline (24803.374 us; speedup 1.0000x reference)
//
#include <hip/hip_runtime.h>

// RNN-VAE (enc LSTM -> latent -> dec LSTM -> proj) on MI355X.
// Strategy: 16 WGs x 16 batch rows each; full recurrence inside one WG
// (no inter-WG sync). Weights pre-packed to bf16 MFMA B-fragments once per
// launch; U streams from L2 each step (fits 4MB/XCD L2). All side GEMMs
// (x@W_enc, x@W_dec[:64], h_fin@W_dec[64:], h@W_out) fused into the two
// recurrence kernels. c/gates fp32, h stored bf16 for MFMA.

typedef __bf16 bf16x8 __attribute__((ext_vector_type(8)));
typedef float f32x4 __attribute__((ext_vector_type(4)));
typedef unsigned int uint4v __attribute__((ext_vector_type(4)));

#define DI __device__ __forceinline__

DI unsigned short f2bf(float f) {            // fp32 -> bf16 RNE
  unsigned int u = __float_as_uint(f);
  u += 0x7fffu + ((u >> 16) & 1u);
  return (unsigned short)(u >> 16);
}

union FragU { bf16x8 v; unsigned short us[8]; unsigned int w[4]; };

DI f32x4 mfma16(bf16x8 a, bf16x8 b, f32x4 c) {
  // D[row=(lane>>4)*4+q][col=lane&15]; A[row=lane&15][k=(lane>>4)*8+j];
  // B[k=(lane>>4)*8+j][col=lane&15]
  return __builtin_amdgcn_mfma_f32_16x16x32_bf16(a, b, c, 0, 0, 0);
}

// ---- weight fragment packing: src (K x N fp32, row-major) ->
// frags [kt][nt][lane][8 bf16], frag[j] = src[kt*32+(lane>>4)*8+j][nt*16+(lane&15)]
__global__ void pack_frags(const float* __restrict__ src,
                           unsigned short* __restrict__ dst, int K, int N) {
  int KT = K >> 5, NT = N >> 4;
  int total = KT * NT * 64;
  for (int idx = blockIdx.x * blockDim.x + threadIdx.x; idx < total;
       idx += gridDim.x * blockDim.x) {
    int lane = idx & 63;
    int fi = idx >> 6;
    int nt = fi % NT;
    int kt = fi / NT;
    int r0 = kt * 32 + (lane >> 4) * 8;
    int col = nt * 16 + (lane & 15);
    unsigned int w[4];
#pragma unroll
    for (int p = 0; p < 4; ++p) {
      unsigned int lo = f2bf(src[(size_t)(r0 + 2 * p) * N + col]);
      unsigned int hi = f2bf(src[(size_t)(r0 + 2 * p + 1) * N + col]);
      w[p] = lo | (hi << 16);
    }
    *(uint4v*)(dst + (size_t)idx * 8) = (uint4v){w[0], w[1], w[2], w[3]};
  }
}

// ---------------- encoder: fused x@W_enc + b_enc, LSTM(relu), mask ---------
__global__ __launch_bounds__(512, 2)
void enc_rnn(const float* __restrict__ x,              // [256][1024][128]
             const unsigned short* __restrict__ Wef,   // [4][64] frags (128x1024)
             const unsigned short* __restrict__ Uef,   // [8][64] frags (256x1024)
             const float* __restrict__ benc,           // [1024]
             unsigned short* __restrict__ hfin) {      // [16][8][64][8] bf16 frags
  __shared__ __align__(16) float gates[4][16][260];      // +4 pad: 2-way banks
  __shared__ __align__(16) unsigned short hfrag[8][64][8]; // h in A-frag layout

  const int tid = threadIdx.x;
  const int wave = tid >> 6, lane = tid & 63;
  const int lrow = lane & 15, lkg = lane >> 4;
  const int b0 = blockIdx.x * 16;
  const int gate = wave >> 1;                 // 0=i 1=f 2=g 3=o
  const int jblock = wave * 4 + lkg;          // owned h-col block (8 cols)
  const int j0 = jblock * 8;
  unsigned short* hw = &hfrag[jblock >> 2][(jblock & 3) * 16 + lrow][0];

  ((uint4v*)hfrag)[tid] = (uint4v){0u, 0u, 0u, 0u};   // h0 = 0

  float bfr[8];
#pragma unroll
  for (int i = 0; i < 8; ++i) bfr[i] = benc[(wave * 8 + i) * 16 + lrow];

  float c[8];
#pragma unroll
  for (int j = 0; j < 8; ++j) c[j] = 0.f;

  const bf16x8* Wl = (const bf16x8*)Wef + lane;
  const bf16x8* Ul = (const bf16x8*)Uef + lane;
  const float* xbase = x + (size_t)(b0 + lrow) * 1024 * 128 + lkg * 8;

  __syncthreads();

  for (int t = 0; t < 1024; ++t) {
    const float* xp = xbase + (size_t)t * 128;
    float4 xa[4][2];
#pragma unroll
    for (int kt = 0; kt < 4; ++kt) {
      xa[kt][0] = *(const float4*)(xp + kt * 32);
      xa[kt][1] = *(const float4*)(xp + kt * 32 + 4);
    }
    bool nz = false;
#pragma unroll
    for (int kt = 0; kt < 4; ++kt)
      nz = nz || xa[kt][0].x != 0.f || xa[kt][0].y != 0.f || xa[kt][0].z != 0.f ||
           xa[kt][0].w != 0.f || xa[kt][1].x != 0.f || xa[kt][1].y != 0.f ||
           xa[kt][1].z != 0.f || xa[kt][1].w != 0.f;
    unsigned long long ballot = __ballot((int)nz);
    if (ballot == 0ull) continue;   // all 16 rows masked: carry h,c (uniform)

    FragU xf[4];
#pragma unroll
    for (int kt = 0; kt < 4; ++kt) {
      xf[kt].us[0] = f2bf(xa[kt][0].x); xf[kt].us[1] = f2bf(xa[kt][0].y);
      xf[kt].us[2] = f2bf(xa[kt][0].z); xf[kt].us[3] = f2bf(xa[kt][0].w);
      xf[kt].us[4] = f2bf(xa[kt][1].x); xf[kt].us[5] = f2bf(xa[kt][1].y);
      xf[kt].us[6] = f2bf(xa[kt][1].z); xf[kt].us[7] = f2bf(xa[kt][1].w);
    }
    unsigned long long bc = ballot | (ballot >> 16) | (ballot >> 32) | (ballot >> 48);
    const bool rowm = (bc >> lrow) & 1ull;

    bf16x8 hfr[8];
#pragma unroll
    for (int kt = 0; kt < 8; ++kt) hfr[kt] = *(const bf16x8*)&hfrag[kt][lane][0];

#pragma unroll
    for (int i = 0; i < 8; ++i) {
      const int nt = wave * 8 + i;
      f32x4 acc = {bfr[i], bfr[i], bfr[i], bfr[i]};
#pragma unroll
      for (int kt = 0; kt < 4; ++kt)
        acc = mfma16(xf[kt].v, Wl[(kt * 64 + nt) * 64], acc);
#pragma unroll
      for (int kt = 0; kt < 8; ++kt)
        acc = mfma16(hfr[kt], Ul[(kt * 64 + nt) * 64], acc);
      const int jj = (wave & 1) * 128 + i * 16 + lrow;
#pragma unroll
      for (int q = 0; q < 4; ++q) {
        float v = acc[q];
        v = (gate == 2) ? fmaxf(v, 0.f) : 1.0f / (1.0f + __expf(-v));
        gates[gate][lkg * 4 + q][jj] = v;
      }
    }
    __syncthreads();

    if (rowm) {
      float4 I0 = *(const float4*)&gates[0][lrow][j0];
      float4 I1 = *(const float4*)&gates[0][lrow][j0 + 4];
      float4 F0 = *(const float4*)&gates[1][lrow][j0];
      float4 F1 = *(const float4*)&gates[1][lrow][j0 + 4];
      float4 G0 = *(const float4*)&gates[2][lrow][j0];
      float4 G1 = *(const float4*)&gates[2][lrow][j0 + 4];
      float4 O0 = *(const float4*)&gates[3][lrow][j0];
      float4 O1 = *(const float4*)&gates[3][lrow][j0 + 4];
      float iv[8] = {I0.x, I0.y, I0.z, I0.w, I1.x, I1.y, I1.z, I1.w};
      float fv[8] = {F0.x, F0.y, F0.z, F0.w, F1.x, F1.y, F1.z, F1.w};
      float gv[8] = {G0.x, G0.y, G0.z, G0.w, G1.x, G1.y, G1.z, G1.w};
      float ov[8] = {O0.x, O0.y, O0.z, O0.w, O1.x, O1.y, O1.z, O1.w};
      unsigned int hp[4];
#pragma unroll
      for (int p = 0; p < 4; ++p) {
        float c0 = fv[2 * p] * c[2 * p] + iv[2 * p] * gv[2 * p];
        float c1 = fv[2 * p + 1] * c[2 * p + 1] + iv[2 * p + 1] * gv[2 * p + 1];
        c[2 * p] = c0; c[2 * p + 1] = c1;
        unsigned int h0 = f2bf(ov[2 * p] * fmaxf(c0, 0.f));
        unsigned int h1 = f2bf(ov[2 * p + 1] * fmaxf(c1, 0.f));
        hp[p] = h0 | (h1 << 16);
      }
      *(uint4v*)hw = (uint4v){hp[0], hp[1], hp[2], hp[3]};
    }
    __syncthreads();
  }

  ((uint4v*)hfin)[(size_t)blockIdx.x * 512 + tid] = ((const uint4v*)hfrag)[tid];
}

// -------- decoder: fused x[:64]@Wd0 + latW, LSTM(relu), h@W_out + b_out ----
__global__ __launch_bounds__(512, 2)
void dec_rnn(const float* __restrict__ x,
             const unsigned short* __restrict__ Wd0f,   // [2][64] (64x1024)
             const unsigned short* __restrict__ WdLf,   // [8][64] (256x1024)
             const unsigned short* __restrict__ Udf,    // [8][64] (256x1024)
             const float* __restrict__ bdec,
             const unsigned short* __restrict__ Wof,    // [8][4]  (256x64)
             const float* __restrict__ bout,
             const unsigned short* __restrict__ hfin,
             float* __restrict__ out) {                 // [256][1024][64]
  __shared__ __align__(16) float gates[4][16][260];
  __shared__ __align__(16) unsigned short hfrag[8][64][8];

  const int tid = threadIdx.x;
  const int wave = tid >> 6, lane = tid & 63;
  const int lrow = lane & 15, lkg = lane >> 4;
  const int b0 = blockIdx.x * 16;
  const int gate = wave >> 1;
  const int jblock = wave * 4 + lkg;
  const int j0 = jblock * 8;
  unsigned short* hw = &hfrag[jblock >> 2][(jblock & 3) * 16 + lrow][0];

  ((uint4v*)hfrag)[tid] = (uint4v){0u, 0u, 0u, 0u};

  const bf16x8* W0l = (const bf16x8*)Wd0f + lane;
  const bf16x8* WLl = (const bf16x8*)WdLf + lane;
  const bf16x8* Ul  = (const bf16x8*)Udf + lane;

  // latW[i] = b_dec + h_fin @ W_dec[64:] (kept in regs; step z starts here)
  bf16x8 ha[8];
#pragma unroll
  for (int kt = 0; kt < 8; ++kt)
    ha[kt] = *(const bf16x8*)(hfin + (size_t)blockIdx.x * 4096 +
                              (size_t)(kt * 64 + lane) * 8);
  f32x4 lat[8];
#pragma unroll
  for (int i = 0; i < 8; ++i) {
    const int nt = wave * 8 + i;
    float bd = bdec[nt * 16 + lrow];
    lat[i] = (f32x4){bd, bd, bd, bd};
#pragma unroll
    for (int kt = 0; kt < 8; ++kt)
      lat[i] = mfma16(ha[kt], WLl[(kt * 64 + nt) * 64], lat[i]);
  }

  const int w4 = wave & 3;
  bf16x8 wo[8];
#pragma unroll
  for (int kt = 0; kt < 8; ++kt)
    wo[kt] = ((const bf16x8*)Wof)[(kt * 4 + w4) * 64 + lane];
  const float bo = bout[w4 * 16 + lrow];

  float c[8];
#pragma unroll
  for (int j = 0; j < 8; ++j) c[j] = 0.f;

  const float* xbase = x + (size_t)(b0 + lrow) * 1024 * 128 + lkg * 8;

  __syncthreads();

  for (int t = 0; t < 1024; ++t) {
    const float* xp = xbase + (size_t)t * 128;
    FragU xf[2];
#pragma unroll
    for (int kt = 0; kt < 2; ++kt) {
      float4 a = *(const float4*)(xp + kt * 32);
      float4 b = *(const float4*)(xp + kt * 32 + 4);
      xf[kt].us[0] = f2bf(a.x); xf[kt].us[1] = f2bf(a.y);
      xf[kt].us[2] = f2bf(a.z); xf[kt].us[3] = f2bf(a.w);
      xf[kt].us[4] = f2bf(b.x); xf[kt].us[5] = f2bf(b.y);
      xf[kt].us[6] = f2bf(b.z); xf[kt].us[7] = f2bf(b.w);
    }
    bf16x8 hfr[8];
#pragma unroll
    for (int kt = 0; kt < 8; ++kt) hfr[kt] = *(const bf16x8*)&hfrag[kt][lane][0];

#pragma unroll
    for (int i = 0; i < 8; ++i) {
      const int nt = wave * 8 + i;
      f32x4 acc = lat[i];
#pragma unroll
      for (int kt = 0; kt < 2; ++kt)
        acc = mfma16(xf[kt].v, W0l[(kt * 64 + nt) * 64], acc);
#pragma unroll
      for (int kt = 0; kt < 8; ++kt)
        acc = mfma16(hfr[kt], Ul[(kt * 64 + nt) * 64], acc);
      const int jj = (wave & 1) * 128 + i * 16 + lrow;
#pragma unroll
      for (int q = 0; q < 4; ++q) {
        float v = acc[q];
        v = (gate == 2) ? fmaxf(v, 0.f) : 1.0f / (1.0f + __expf(-v));
        gates[gate][lkg * 4 + q][jj] = v;
      }
    }
    __syncthreads();

    {
      float4 I0 = *(const float4*)&gates[0][lrow][j0];
      float4 I1 = *(const float4*)&gates[0][lrow][j0 + 4];
      float4 F0 = *(const float4*)&gates[1][lrow][j0];
      float4 F1 = *(const float4*)&gates[1][lrow][j0 + 4];
      float4 G0 = *(const float4*)&gates[2][lrow][j0];
      float4 G1 = *(const float4*)&gates[2][lrow][j0 + 4];
      float4 O0 = *(const float4*)&gates[3][lrow][j0];
      float4 O1 = *(const float4*)&gates[3][lrow][j0 + 4];
      float iv[8] = {I0.x, I0.y, I0.z, I0.w, I1.x, I1.y, I1.z, I1.w};
      float fv[8] = {F0.x, F0.y, F0.z, F0.w, F1.x, F1.y, F1.z, F1.w};
      float gv[8] = {G0.x, G0.y, G0.z, G0.w, G1.x, G1.y, G1.z, G1.w};
      float ov[8] = {O0.x, O0.y, O0.z, O0.w, O1.x, O1.y, O1.z, O1.w};
      unsigned int hp[4];
#pragma unroll
      for (int p = 0; p < 4; ++p) {
        float c0 = fv[2 * p] * c[2 * p] + iv[2 * p] * gv[2 * p];
        float c1 = fv[2 * p + 1] * c[2 * p + 1] + iv[2 * p + 1] * gv[2 * p + 1];
        c[2 * p] = c0; c[2 * p + 1] = c1;
        unsigned int h0 = f2bf(ov[2 * p] * fmaxf(c0, 0.f));
        unsigned int h1 = f2bf(ov[2 * p + 1] * fmaxf(c1, 0.f));
        hp[p] = h0 | (h1 << 16);
      }
      *(uint4v*)hw = (uint4v){hp[0], hp[1], hp[2], hp[3]};
    }
    __syncthreads();

    if (wave < 4) {   // fused output projection: out[b,t,:] = h_t @ W_out + b_out
      bf16x8 h2[8];
#pragma unroll
      for (int kt = 0; kt < 8; ++kt) h2[kt] = *(const bf16x8*)&hfrag[kt][lane][0];
      f32x4 oa = {bo, bo, bo, bo};
#pragma unroll
      for (int kt = 0; kt < 8; ++kt) oa = mfma16(h2[kt], wo[kt], oa);
#pragma unroll
      for (int q = 0; q < 4; ++q)
        out[((size_t)(b0 + lkg * 4 + q) * 1024 + t) * 64 + wave * 16 + lrow] = oa[q];
    }
  }
}

extern "C" void kernel_launch(void* const* d_in, const int* in_sizes, int n_in,
                              void* d_out, int out_size, void* d_ws, size_t ws_size,
                              hipStream_t stream) {
  const float* inputs = (const float*)d_in[0];
  const float* W_enc  = (const float*)d_in[1];
  const float* U_enc  = (const float*)d_in[2];
  const float* b_enc  = (const float*)d_in[3];
  const float* W_dec  = (const float*)d_in[4];
  const float* U_dec  = (const float*)d_in[5];
  const float* b_dec  = (const float*)d_in[6];
  const float* W_out  = (const float*)d_in[7];
  const float* b_out  = (const float*)d_in[8];

  char* ws = (char*)d_ws;
  unsigned short* Uef  = (unsigned short*)(ws + 0);        // 256x1024 -> 512KB
  unsigned short* Udf  = (unsigned short*)(ws + 524288);   // 512KB
  unsigned short* Wef  = (unsigned short*)(ws + 1048576);  // 128x1024 -> 256KB
  unsigned short* Wd0f = (unsigned short*)(ws + 1310720);  // 64x1024  -> 128KB
  unsigned short* WdLf = (unsigned short*)(ws + 1441792);  // 256x1024 -> 512KB
  unsigned short* Wof  = (unsigned short*)(ws + 1966080);  // 256x64   -> 32KB
  unsigned short* hfin = (unsigned short*)(ws + 1998848);  // 16 WGs x 8KB

  pack_frags<<<128, 256, 0, stream>>>(U_enc, Uef, 256, 1024);
  pack_frags<<<128, 256, 0, stream>>>(U_dec, Udf, 256, 1024);
  pack_frags<<<128, 256, 0, stream>>>(W_enc, Wef, 128, 1024);
  pack_frags<<<128, 256, 0, stream>>>(W_dec, Wd0f, 64, 1024);
  pack_frags<<<128, 256, 0, stream>>>(W_dec + 64 * 1024, WdLf, 256, 1024);
  pack_frags<<<32, 256, 0, stream>>>(W_out, Wof, 256, 64);

  enc_rnn<<<16, 512, 0, stream>>>(inputs, Wef, Uef, b_enc, hfin);
  dec_rnn<<<16, 512, 0, stream>>>(inputs, Wd0f, WdLf, Udf, b_dec, Wof, b_out,
                                  hfin, (float*)d_out);
}

// Round 2
// 20730.557 us; speedup vs baseline: 1.1965x; 1.1965x over previous
//
#include <hip/hip_runtime.h>

// RNN-VAE on MI355X. 16 WGs x 16 batch rows, full recurrence per WG.
// R2: cut per-step L2 streaming: reg-pin W frags (t-invariant), LDS-pin
// U[kt=0] slice (64KB) + half of W_out (dec), double-buffered explicit
// prefetch of remaining U frags across i-iterations and across the step
// boundary (U addresses are t-invariant, so i=0 prefetch issues at i=7).

typedef __bf16 bf16x8 __attribute__((ext_vector_type(8)));
typedef float f32x4 __attribute__((ext_vector_type(4)));
typedef unsigned int uint4v __attribute__((ext_vector_type(4)));

#define DI __device__ __forceinline__

DI unsigned short f2bf(float f) {            // fp32 -> bf16 RNE
  unsigned int u = __float_as_uint(f);
  u += 0x7fffu + ((u >> 16) & 1u);
  return (unsigned short)(u >> 16);
}

union FragU { bf16x8 v; unsigned short us[8]; unsigned int w[4]; };

DI f32x4 mfma16(bf16x8 a, bf16x8 b, f32x4 c) {
  // D[row=(lane>>4)*4+q][col=lane&15]; A[row=lane&15][k=(lane>>4)*8+j]
  return __builtin_amdgcn_mfma_f32_16x16x32_bf16(a, b, c, 0, 0, 0);
}

// ---- weight fragment packing: src (K x N fp32, row-major) ->
// frag[j] = src[kt*32+(lane>>4)*8+j][nt*16+(lane&15)], flat idx (kt*NT+nt)*64+lane
__global__ void pack_frags(const float* __restrict__ src,
                           unsigned short* __restrict__ dst, int K, int N) {
  int KT = K >> 5, NT = N >> 4;
  int total = KT * NT * 64;
  for (int idx = blockIdx.x * blockDim.x + threadIdx.x; idx < total;
       idx += gridDim.x * blockDim.x) {
    int lane = idx & 63;
    int fi = idx >> 6;
    int nt = fi % NT;
    int kt = fi / NT;
    int r0 = kt * 32 + (lane >> 4) * 8;
    int col = nt * 16 + (lane & 15);
    unsigned int w[4];
#pragma unroll
    for (int p = 0; p < 4; ++p) {
      unsigned int lo = f2bf(src[(size_t)(r0 + 2 * p) * N + col]);
      unsigned int hi = f2bf(src[(size_t)(r0 + 2 * p + 1) * N + col]);
      w[p] = lo | (hi << 16);
    }
    *(uint4v*)(dst + (size_t)idx * 8) = (uint4v){w[0], w[1], w[2], w[3]};
  }
}

// =========================== encoder ======================================
// streamed per i: B[0]=W kt2, B[1]=W kt3, B[2..8]=U kt1..7
#define ENC_LOADS(ii, B) do {                                              \
    const int ntL = wbase + (ii);                                          \
    B[0] = Wl[(2 * 64 + ntL) * 64];                                        \
    B[1] = Wl[(3 * 64 + ntL) * 64];                                        \
    B[2] = Ul[(1 * 64 + ntL) * 64];                                        \
    B[3] = Ul[(2 * 64 + ntL) * 64];                                        \
    B[4] = Ul[(3 * 64 + ntL) * 64];                                        \
    B[5] = Ul[(4 * 64 + ntL) * 64];                                        \
    B[6] = Ul[(5 * 64 + ntL) * 64];                                        \
    B[7] = Ul[(6 * 64 + ntL) * 64];                                        \
    B[8] = Ul[(7 * 64 + ntL) * 64];                                        \
  } while (0)

#define ENC_STEP(ii, CUR, NXT) do {                                        \
    ENC_LOADS(((ii) < 7 ? (ii) + 1 : 0), NXT);                             \
    const int ntS = wbase + (ii);                                          \
    bf16x8 u0_ = *(const bf16x8*)&ulds[(ntS * 64 + lane) * 8];             \
    f32x4 acc = {bfr[ii], bfr[ii], bfr[ii], bfr[ii]};                      \
    acc = mfma16(xf[0].v, wp0[ii], acc);                                   \
    acc = mfma16(xf[1].v, wp1[ii], acc);                                   \
    acc = mfma16(hfr[0], u0_, acc);                                        \
    acc = mfma16(xf[2].v, CUR[0], acc);                                    \
    acc = mfma16(xf[3].v, CUR[1], acc);                                    \
    acc = mfma16(hfr[1], CUR[2], acc);                                     \
    acc = mfma16(hfr[2], CUR[3], acc);                                     \
    acc = mfma16(hfr[3], CUR[4], acc);                                     \
    acc = mfma16(hfr[4], CUR[5], acc);                                     \
    acc = mfma16(hfr[5], CUR[6], acc);                                     \
    acc = mfma16(hfr[6], CUR[7], acc);                                     \
    acc = mfma16(hfr[7], CUR[8], acc);                                     \
    const int jj = (wave & 1) * 128 + (ii) * 16 + lrow;                    \
    _Pragma("unroll")                                                      \
    for (int q = 0; q < 4; ++q) {                                          \
      float v = acc[q];                                                    \
      v = (gate == 2) ? fmaxf(v, 0.f) : 1.0f / (1.0f + __expf(-v));        \
      gates[gate][lkg * 4 + q][jj] = v;                                    \
    }                                                                      \
  } while (0)

__global__ __launch_bounds__(512, 2)
void enc_rnn(const float* __restrict__ x,              // [256][1024][128]
             const unsigned short* __restrict__ Wef,   // 128x1024 frags
             const unsigned short* __restrict__ Uef,   // 256x1024 frags
             const float* __restrict__ benc,
             unsigned short* __restrict__ hfin) {
  __shared__ __align__(16) float gates[4][16][260];
  __shared__ __align__(16) unsigned short hfrag[8][64][8];
  __shared__ __align__(16) unsigned short ulds[64 * 64 * 8];   // U kt=0, 64KB

  const int tid = threadIdx.x;
  const int wave = tid >> 6, lane = tid & 63;
  const int lrow = lane & 15, lkg = lane >> 4;
  const int b0 = blockIdx.x * 16;
  const int gate = wave >> 1;
  const int wbase = wave * 8;
  const int jblock = wave * 4 + lkg;
  const int j0 = jblock * 8;
  unsigned short* hw = &hfrag[jblock >> 2][(jblock & 3) * 16 + lrow][0];

  ((uint4v*)hfrag)[tid] = (uint4v){0u, 0u, 0u, 0u};
#pragma unroll
  for (int k = 0; k < 8; ++k)   // U kt=0 slice is the first 64KB of Uef
    ((uint4v*)ulds)[tid + k * 512] = ((const uint4v*)Uef)[tid + k * 512];

  const bf16x8* Wl = (const bf16x8*)Wef + lane;
  const bf16x8* Ul = (const bf16x8*)Uef + lane;

  bf16x8 wp0[8], wp1[8];                        // reg-pinned W kt=0,1
#pragma unroll
  for (int i = 0; i < 8; ++i) {
    wp0[i] = Wl[(0 * 64 + wbase + i) * 64];
    wp1[i] = Wl[(1 * 64 + wbase + i) * 64];
  }

  float bfr[8];
#pragma unroll
  for (int i = 0; i < 8; ++i) bfr[i] = benc[(wbase + i) * 16 + lrow];

  float c[8];
#pragma unroll
  for (int j = 0; j < 8; ++j) c[j] = 0.f;

  const float* xbase = x + (size_t)(b0 + lrow) * 1024 * 128 + lkg * 8;

  bf16x8 bufA[9], bufB[9];
  ENC_LOADS(0, bufA);

  __syncthreads();

  for (int t = 0; t < 1024; ++t) {
    const float* xp = xbase + (size_t)t * 128;
    float4 xa[4][2];
#pragma unroll
    for (int kt = 0; kt < 4; ++kt) {
      xa[kt][0] = *(const float4*)(xp + kt * 32);
      xa[kt][1] = *(const float4*)(xp + kt * 32 + 4);
    }
    bool nz = false;
#pragma unroll
    for (int kt = 0; kt < 4; ++kt)
      nz = nz || xa[kt][0].x != 0.f || xa[kt][0].y != 0.f || xa[kt][0].z != 0.f ||
           xa[kt][0].w != 0.f || xa[kt][1].x != 0.f || xa[kt][1].y != 0.f ||
           xa[kt][1].z != 0.f || xa[kt][1].w != 0.f;
    unsigned long long ballot = __ballot((int)nz);
    if (ballot == 0ull) continue;   // masked step: carry h,c (bufA stays valid)

    FragU xf[4];
#pragma unroll
    for (int kt = 0; kt < 4; ++kt) {
      xf[kt].us[0] = f2bf(xa[kt][0].x); xf[kt].us[1] = f2bf(xa[kt][0].y);
      xf[kt].us[2] = f2bf(xa[kt][0].z); xf[kt].us[3] = f2bf(xa[kt][0].w);
      xf[kt].us[4] = f2bf(xa[kt][1].x); xf[kt].us[5] = f2bf(xa[kt][1].y);
      xf[kt].us[6] = f2bf(xa[kt][1].z); xf[kt].us[7] = f2bf(xa[kt][1].w);
    }
    unsigned long long bc = ballot | (ballot >> 16) | (ballot >> 32) | (ballot >> 48);
    const bool rowm = (bc >> lrow) & 1ull;

    bf16x8 hfr[8];
#pragma unroll
    for (int kt = 0; kt < 8; ++kt) hfr[kt] = *(const bf16x8*)&hfrag[kt][lane][0];

    ENC_STEP(0, bufA, bufB);
    ENC_STEP(1, bufB, bufA);
    ENC_STEP(2, bufA, bufB);
    ENC_STEP(3, bufB, bufA);
    ENC_STEP(4, bufA, bufB);
    ENC_STEP(5, bufB, bufA);
    ENC_STEP(6, bufA, bufB);
    ENC_STEP(7, bufB, bufA);   // also re-issues i=0 loads for next step
    __syncthreads();

    if (rowm) {
      float4 I0 = *(const float4*)&gates[0][lrow][j0];
      float4 I1 = *(const float4*)&gates[0][lrow][j0 + 4];
      float4 F0 = *(const float4*)&gates[1][lrow][j0];
      float4 F1 = *(const float4*)&gates[1][lrow][j0 + 4];
      float4 G0 = *(const float4*)&gates[2][lrow][j0];
      float4 G1 = *(const float4*)&gates[2][lrow][j0 + 4];
      float4 O0 = *(const float4*)&gates[3][lrow][j0];
      float4 O1 = *(const float4*)&gates[3][lrow][j0 + 4];
      float iv[8] = {I0.x, I0.y, I0.z, I0.w, I1.x, I1.y, I1.z, I1.w};
      float fv[8] = {F0.x, F0.y, F0.z, F0.w, F1.x, F1.y, F1.z, F1.w};
      float gv[8] = {G0.x, G0.y, G0.z, G0.w, G1.x, G1.y, G1.z, G1.w};
      float ov[8] = {O0.x, O0.y, O0.z, O0.w, O1.x, O1.y, O1.z, O1.w};
      unsigned int hp[4];
#pragma unroll
      for (int p = 0; p < 4; ++p) {
        float c0 = fv[2 * p] * c[2 * p] + iv[2 * p] * gv[2 * p];
        float c1 = fv[2 * p + 1] * c[2 * p + 1] + iv[2 * p + 1] * gv[2 * p + 1];
        c[2 * p] = c0; c[2 * p + 1] = c1;
        unsigned int h0 = f2bf(ov[2 * p] * fmaxf(c0, 0.f));
        unsigned int h1 = f2bf(ov[2 * p + 1] * fmaxf(c1, 0.f));
        hp[p] = h0 | (h1 << 16);
      }
      *(uint4v*)hw = (uint4v){hp[0], hp[1], hp[2], hp[3]};
    }
    __syncthreads();
  }

  ((uint4v*)hfin)[(size_t)blockIdx.x * 512 + tid] = ((const uint4v*)hfrag)[tid];
}

// =========================== decoder ======================================
// streamed per i: B[0..6] = U kt1..7
#define DEC_LOADS(ii, B) do {                                              \
    const int ntL = wbase + (ii);                                          \
    B[0] = Ul[(1 * 64 + ntL) * 64];                                        \
    B[1] = Ul[(2 * 64 + ntL) * 64];                                        \
    B[2] = Ul[(3 * 64 + ntL) * 64];                                        \
    B[3] = Ul[(4 * 64 + ntL) * 64];                                        \
    B[4] = Ul[(5 * 64 + ntL) * 64];                                        \
    B[5] = Ul[(6 * 64 + ntL) * 64];                                        \
    B[6] = Ul[(7 * 64 + ntL) * 64];                                        \
  } while (0)

#define DEC_STEP(ii, CUR, NXT) do {                                        \
    DEC_LOADS(((ii) < 7 ? (ii) + 1 : 0), NXT);                             \
    const int ntS = wbase + (ii);                                          \
    bf16x8 u0_ = *(const bf16x8*)&ulds[(ntS * 64 + lane) * 8];             \
    f32x4 acc = lat[ii];                                                   \
    acc = mfma16(xf[0].v, w0p0[ii], acc);                                  \
    acc = mfma16(xf[1].v, w0p1[ii], acc);                                  \
    acc = mfma16(hfr[0], u0_, acc);                                        \
    acc = mfma16(hfr[1], CUR[0], acc);                                     \
    acc = mfma16(hfr[2], CUR[1], acc);                                     \
    acc = mfma16(hfr[3], CUR[2], acc);                                     \
    acc = mfma16(hfr[4], CUR[3], acc);                                     \
    acc = mfma16(hfr[5], CUR[4], acc);                                     \
    acc = mfma16(hfr[6], CUR[5], acc);                                     \
    acc = mfma16(hfr[7], CUR[6], acc);                                     \
    const int jj = (wave & 1) * 128 + (ii) * 16 + lrow;                    \
    _Pragma("unroll")                                                      \
    for (int q = 0; q < 4; ++q) {                                          \
      float v = acc[q];                                                    \
      v = (gate == 2) ? fmaxf(v, 0.f) : 1.0f / (1.0f + __expf(-v));        \
      gates[gate][lkg * 4 + q][jj] = v;                                    \
    }                                                                      \
  } while (0)

__global__ __launch_bounds__(512, 2)
void dec_rnn(const float* __restrict__ x,
             const unsigned short* __restrict__ Wd0f,   // 64x1024 frags
             const unsigned short* __restrict__ WdLf,   // 256x1024 frags
             const unsigned short* __restrict__ Udf,    // 256x1024 frags
             const float* __restrict__ bdec,
             const unsigned short* __restrict__ Wof,    // 256x64 frags
             const float* __restrict__ bout,
             const unsigned short* __restrict__ hfin,
             float* __restrict__ out) {
  __shared__ __align__(16) float gates[4][16][260];
  __shared__ __align__(16) unsigned short hfrag[8][64][8];
  __shared__ __align__(16) unsigned short ulds[64 * 64 * 8];   // U kt=0, 64KB
  __shared__ __align__(16) unsigned short wolds[16 * 64 * 8];  // Wout kt0..3, 16KB

  const int tid = threadIdx.x;
  const int wave = tid >> 6, lane = tid & 63;
  const int lrow = lane & 15, lkg = lane >> 4;
  const int b0 = blockIdx.x * 16;
  const int gate = wave >> 1;
  const int wbase = wave * 8;
  const int jblock = wave * 4 + lkg;
  const int j0 = jblock * 8;
  unsigned short* hw = &hfrag[jblock >> 2][(jblock & 3) * 16 + lrow][0];

  ((uint4v*)hfrag)[tid] = (uint4v){0u, 0u, 0u, 0u};
#pragma unroll
  for (int k = 0; k < 8; ++k)
    ((uint4v*)ulds)[tid + k * 512] = ((const uint4v*)Udf)[tid + k * 512];
  ((uint4v*)wolds)[tid] = ((const uint4v*)Wof)[tid];
  ((uint4v*)wolds)[tid + 512] = ((const uint4v*)Wof)[tid + 512];

  const bf16x8* W0l = (const bf16x8*)Wd0f + lane;
  const bf16x8* WLl = (const bf16x8*)WdLf + lane;
  const bf16x8* Ul  = (const bf16x8*)Udf + lane;

  bf16x8 w0p0[8], w0p1[8];                      // reg-pinned W_dec[:64] kt=0,1
#pragma unroll
  for (int i = 0; i < 8; ++i) {
    w0p0[i] = W0l[(0 * 64 + wbase + i) * 64];
    w0p1[i] = W0l[(1 * 64 + wbase + i) * 64];
  }

  // latW[i] = b_dec + h_fin @ W_dec[64:]
  bf16x8 ha[8];
#pragma unroll
  for (int kt = 0; kt < 8; ++kt)
    ha[kt] = *(const bf16x8*)(hfin + (size_t)blockIdx.x * 4096 +
                              (size_t)(kt * 64 + lane) * 8);
  f32x4 lat[8];
#pragma unroll
  for (int i = 0; i < 8; ++i) {
    const int nt = wbase + i;
    float bd = bdec[nt * 16 + lrow];
    lat[i] = (f32x4){bd, bd, bd, bd};
#pragma unroll
    for (int kt = 0; kt < 8; ++kt)
      lat[i] = mfma16(ha[kt], WLl[(kt * 64 + nt) * 64], lat[i]);
  }

  const int w4 = wave & 3;
  bf16x8 wop[4];                                // reg-pinned Wout kt4..7
#pragma unroll
  for (int k = 0; k < 4; ++k)
    wop[k] = ((const bf16x8*)Wof)[((k + 4) * 4 + w4) * 64 + lane];
  const float bo = bout[w4 * 16 + lrow];

  float c[8];
#pragma unroll
  for (int j = 0; j < 8; ++j) c[j] = 0.f;

  const float* xbase = x + (size_t)(b0 + lrow) * 1024 * 128 + lkg * 8;

  bf16x8 bufA[7], bufB[7];
  DEC_LOADS(0, bufA);

  __syncthreads();

  for (int t = 0; t < 1024; ++t) {
    const float* xp = xbase + (size_t)t * 128;
    FragU xf[2];
#pragma unroll
    for (int kt = 0; kt < 2; ++kt) {
      float4 a = *(const float4*)(xp + kt * 32);
      float4 b = *(const float4*)(xp + kt * 32 + 4);
      xf[kt].us[0] = f2bf(a.x); xf[kt].us[1] = f2bf(a.y);
      xf[kt].us[2] = f2bf(a.z); xf[kt].us[3] = f2bf(a.w);
      xf[kt].us[4] = f2bf(b.x); xf[kt].us[5] = f2bf(b.y);
      xf[kt].us[6] = f2bf(b.z); xf[kt].us[7] = f2bf(b.w);
    }
    bf16x8 hfr[8];
#pragma unroll
    for (int kt = 0; kt < 8; ++kt) hfr[kt] = *(const bf16x8*)&hfrag[kt][lane][0];

    DEC_STEP(0, bufA, bufB);
    DEC_STEP(1, bufB, bufA);
    DEC_STEP(2, bufA, bufB);
    DEC_STEP(3, bufB, bufA);
    DEC_STEP(4, bufA, bufB);
    DEC_STEP(5, bufB, bufA);
    DEC_STEP(6, bufA, bufB);
    DEC_STEP(7, bufB, bufA);   // re-issues i=0 loads for next step
    __syncthreads();

    {
      float4 I0 = *(const float4*)&gates[0][lrow][j0];
      float4 I1 = *(const float4*)&gates[0][lrow][j0 + 4];
      float4 F0 = *(const float4*)&gates[1][lrow][j0];
      float4 F1 = *(const float4*)&gates[1][lrow][j0 + 4];
      float4 G0 = *(const float4*)&gates[2][lrow][j0];
      float4 G1 = *(const float4*)&gates[2][lrow][j0 + 4];
      float4 O0 = *(const float4*)&gates[3][lrow][j0];
      float4 O1 = *(const float4*)&gates[3][lrow][j0 + 4];
      float iv[8] = {I0.x, I0.y, I0.z, I0.w, I1.x, I1.y, I1.z, I1.w};
      float fv[8] = {F0.x, F0.y, F0.z, F0.w, F1.x, F1.y, F1.z, F1.w};
      float gv[8] = {G0.x, G0.y, G0.z, G0.w, G1.x, G1.y, G1.z, G1.w};
      float ov[8] = {O0.x, O0.y, O0.z, O0.w, O1.x, O1.y, O1.z, O1.w};
      unsigned int hp[4];
#pragma unroll
      for (int p = 0; p < 4; ++p) {
        float c0 = fv[2 * p] * c[2 * p] + iv[2 * p] * gv[2 * p];
        float c1 = fv[2 * p + 1] * c[2 * p + 1] + iv[2 * p + 1] * gv[2 * p + 1];
        c[2 * p] = c0; c[2 * p + 1] = c1;
        unsigned int h0 = f2bf(ov[2 * p] * fmaxf(c0, 0.f));
        unsigned int h1 = f2bf(ov[2 * p + 1] * fmaxf(c1, 0.f));
        hp[p] = h0 | (h1 << 16);
      }
      *(uint4v*)hw = (uint4v){hp[0], hp[1], hp[2], hp[3]};
    }
    __syncthreads();

    if (wave < 4) {   // fused out[b,t,:] = h_t @ W_out + b_out
      f32x4 oa = {bo, bo, bo, bo};
#pragma unroll
      for (int kt = 0; kt < 4; ++kt) {
        bf16x8 h2 = *(const bf16x8*)&hfrag[kt][lane][0];
        bf16x8 w_ = *(const bf16x8*)&wolds[((kt * 4 + w4) * 64 + lane) * 8];
        oa = mfma16(h2, w_, oa);
      }
#pragma unroll
      for (int kt = 4; kt < 8; ++kt) {
        bf16x8 h2 = *(const bf16x8*)&hfrag[kt][lane][0];
        oa = mfma16(h2, wop[kt - 4], oa);
      }
#pragma unroll
      for (int q = 0; q < 4; ++q)
        out[((size_t)(b0 + lkg * 4 + q) * 1024 + t) * 64 + wave * 16 + lrow] = oa[q];
    }
  }
}

extern "C" void kernel_launch(void* const* d_in, const int* in_sizes, int n_in,
                              void* d_out, int out_size, void* d_ws, size_t ws_size,
                              hipStream_t stream) {
  const float* inputs = (const float*)d_in[0];
  const float* W_enc  = (const float*)d_in[1];
  const float* U_enc  = (const float*)d_in[2];
  const float* b_enc  = (const float*)d_in[3];
  const float* W_dec  = (const float*)d_in[4];
  const float* U_dec  = (const float*)d_in[5];
  const float* b_dec  = (const float*)d_in[6];
  const float* W_out  = (const float*)d_in[7];
  const float* b_out  = (const float*)d_in[8];

  char* ws = (char*)d_ws;
  unsigned short* Uef  = (unsigned short*)(ws + 0);        // 512KB
  unsigned short* Udf  = (unsigned short*)(ws + 524288);   // 512KB
  unsigned short* Wef  = (unsigned short*)(ws + 1048576);  // 256KB
  unsigned short* Wd0f = (unsigned short*)(ws + 1310720);  // 128KB
  unsigned short* WdLf = (unsigned short*)(ws + 1441792);  // 512KB
  unsigned short* Wof  = (unsigned short*)(ws + 1966080);  // 32KB
  unsigned short* hfin = (unsigned short*)(ws + 1998848);  // 128KB

  pack_frags<<<128, 256, 0, stream>>>(U_enc, Uef, 256, 1024);
  pack_frags<<<128, 256, 0, stream>>>(U_dec, Udf, 256, 1024);
  pack_frags<<<128, 256, 0, stream>>>(W_enc, Wef, 128, 1024);
  pack_frags<<<128, 256, 0, stream>>>(W_dec, Wd0f, 64, 1024);
  pack_frags<<<128, 256, 0, stream>>>(W_dec + 64 * 1024, WdLf, 256, 1024);
  pack_frags<<<32, 256, 0, stream>>>(W_out, Wof, 256, 64);

  enc_rnn<<<16, 512, 0, stream>>>(inputs, Wef, Uef, b_enc, hfin);
  dec_rnn<<<16, 512, 0, stream>>>(inputs, Wd0f, WdLf, Udf, b_dec, Wof, b_out,
                                  hfin, (float*)d_out);
}